// Round 13
// baseline (70.234 us; speedup 1.0000x reference)
//
#include <hip/hip_runtime.h>
#include <hip/hip_bf16.h>

typedef float f32x4 __attribute__((ext_vector_type(4)));

#define B_SZ 1024
#define D_SZ 128
#define C_SZ 100000
#define CPAD 100096          // padded class rows (zero tail), 782*128
#define BM 256
#define BN 128
#define NG 128               // C-tile groups (grid.x)
#define NCT 782              // 100096/128

#define SCALE_F   64.0f
#define MARGIN_F  0.35f
#define CLIP_F    (1.0f - 1e-7f)
#define LOG2E_F   1.4426950408889634f
#define S_LOG2E_F (64.0f * 1.4426950408889634f)

__device__ __forceinline__ void gload_lds16(const void* g, void* l) {
    __builtin_amdgcn_global_load_lds(
        (const __attribute__((address_space(1))) void*)g,
        (__attribute__((address_space(3))) void*)l, 16, 0, 0);
}

// ---- Kernel A: L2-normalize W rows -> fp8 e4m3 (+zero pad) + convert E -> fp8.
// Also zeroes out[0] (accumulated by row_fin's atomicAdd).
__global__ void norm_conv(const float* __restrict__ W, unsigned int* __restrict__ Wf8,
                          const float* __restrict__ E, unsigned int* __restrict__ Ef8,
                          float* __restrict__ out) {
    const int b = blockIdx.x;
    if (b < 12512) {
        const int lane = threadIdx.x & 63;
        const int l32  = lane & 31;
        const int row  = b * 8 + ((threadIdx.x >> 6) << 1) + (lane >> 5);
        if (row < C_SZ) {
            float4 v = reinterpret_cast<const float4*>(W + (size_t)row * D_SZ)[l32];
            float ss = v.x * v.x + v.y * v.y + v.z * v.z + v.w * v.w;
            #pragma unroll
            for (int m = 1; m < 32; m <<= 1) ss += __shfl_xor(ss, m);
            float sc = 1.0f / fmaxf(sqrtf(ss), 1e-12f);
            int r = __builtin_amdgcn_cvt_pk_fp8_f32(v.x * sc, v.y * sc, 0, false);
            r     = __builtin_amdgcn_cvt_pk_fp8_f32(v.z * sc, v.w * sc, r, true);
            Wf8[(size_t)row * 32 + l32] = (unsigned int)r;
        } else {   // zero pad rows [C_SZ, CPAD)
            Wf8[(size_t)row * 32 + l32] = 0u;
        }
    } else {
        if (b == 12512 && threadIdx.x == 0) out[0] = 0.0f;
        const int i = (b - 12512) * 256 + threadIdx.x;   // 32768 float4
        float4 v = reinterpret_cast<const float4*>(E)[i];
        int r = __builtin_amdgcn_cvt_pk_fp8_f32(v.x, v.y, 0, false);
        r     = __builtin_amdgcn_cvt_pk_fp8_f32(v.z, v.w, r, true);
        Ef8[i] = (unsigned int)r;
    }
}

// ---- Kernel C: fused GEMM + exp-sum — R12 fp8 skeleton, BM=256.
// grid (NG=128, 4 bi), 512 thr = 8 waves (4wm x 2wn). Each wave: TWO 32-row
// halves x 64 cols. The staged tile + 16 ds_read/tile now feed 64 MFMA
// (b-frags reused across halves): staging traffic halves, MFMA-per-barrier
// doubles (hides staging latency), ds_read volume unchanged.
// VGPR state: a 32 + acc 64 + rowsum 16 + b 8 ~ 120 < 170 cap -> no spill.
__launch_bounds__(512, 3)
__global__ void gemm_lse(const unsigned char* __restrict__ Ef8,
                         const unsigned char* __restrict__ Wf8,
                         float* __restrict__ P) {
    __shared__ unsigned char sB[2][BN * D_SZ];   // 2 x 16 KB
    __shared__ float rs[2][BM];                  // 2 KB cross-wave reduce

    const int tid  = threadIdx.x;
    const int wave = tid >> 6;
    const int lane = tid & 63;
    const int g4   = lane >> 4;
    const int l15  = lane & 15;
    const int wm   = wave >> 1;           // 0..3 : 32-row slice (per half)
    const int wn   = wave & 1;            // 0..1 : 64-col slice
    const int g    = blockIdx.x;          // 0..127
    const int bi   = blockIdx.y;          // 0..3

    const int T = (NCT - g + NG - 1) / NG;   // 7 for g<14, else 6

    const char* wbase = reinterpret_cast<const char*>(Wf8);
    // staging source (pre-swizzled): LDS linear p=tid*16, row=p>>7 (128B rows),
    // granule=(p&127)>>4; source granule = granule ^ (row&7).
    const int srcOff = ((tid >> 3) << 7) + ((((tid & 7) ^ ((tid >> 3) & 7))) << 4);
    const int ldsOff = wave << 10;        // wave-uniform dest base within 8KB pass

#define STAGE(TI, BUF)                                                         \
    {                                                                          \
        const char* _s = wbase + (size_t)(TI) * 16384 + srcOff;                \
        char* _d = reinterpret_cast<char*>(BUF) + ldsOff;                      \
        gload_lds16(_s,        _d);                                            \
        gload_lds16(_s + 8192, _d + 8192);                                     \
    }

    // ---- stage first B tile
    STAGE(g, sB[0]);

    // ---- A fragments straight from global (once): 8 fp8 = one i64 per frag.
    long a[2][2][4];   // [half][mi][kk]
    {
        const char* ebase = reinterpret_cast<const char*>(Ef8) + (size_t)bi * BM * 128;
        #pragma unroll
        for (int h = 0; h < 2; ++h)
            #pragma unroll
            for (int mi = 0; mi < 2; ++mi) {
                const char* pr = ebase + (h * 128 + wm * 32 + mi * 16 + l15) * 128 + g4 * 8;
                #pragma unroll
                for (int kk = 0; kk < 4; ++kk)
                    a[h][mi][kk] = *reinterpret_cast<const long*>(pr + kk * 32);
            }
    }

    // hoisted ds_read offsets: row = wn*64 + ni*16 + l15 (128B rows);
    // byte = (kk*32 + g4*8) ^ ((l15&7)<<4)   (row&7 == l15&7)
    const int swz = (l15 & 7) << 4;
    int rowb[4];
    #pragma unroll
    for (int ni = 0; ni < 4; ++ni) rowb[ni] = (wn * 64 + ni * 16 + l15) << 7;
    int kb[4];
    #pragma unroll
    for (int kk = 0; kk < 4; ++kk) kb[kk] = (kk * 32 + g4 * 8) ^ swz;

    float rowsum[2][2][4] = {};   // [half][mi][r]

    __syncthreads();

    int cur = 0;
    for (int t = 0; t < T; ++t) {
        if (t + 1 < T) STAGE(g + (t + 1) * NG, sB[cur ^ 1]);

        const char* sBb = reinterpret_cast<const char*>(sB[cur]);
        f32x4 acc[2][2][4] = {};
        #pragma unroll
        for (int kk = 0; kk < 4; ++kk) {
            long b[4];
            #pragma unroll
            for (int ni = 0; ni < 4; ++ni)
                b[ni] = *reinterpret_cast<const long*>(sBb + rowb[ni] + kb[kk]);
            #pragma unroll
            for (int h = 0; h < 2; ++h)
                #pragma unroll
                for (int mi = 0; mi < 2; ++mi)
                    #pragma unroll
                    for (int ni = 0; ni < 4; ++ni)
                        acc[h][mi][ni] = __builtin_amdgcn_mfma_f32_16x16x32_fp8_fp8(
                            a[h][mi][kk], b[ni], acc[h][mi][ni], 0, 0, 0);
        }

        // epilogue: rowsum += exp2(min(x*92.33 - 92.33, 0)).
        // Lower clip free (underflow); upper clip = the fmin (bounds every
        // class contribution at 1 -> also bounds fp8 noise inflation of S).
        #pragma unroll
        for (int h = 0; h < 2; ++h)
            #pragma unroll
            for (int mi = 0; mi < 2; ++mi)
                #pragma unroll
                for (int r = 0; r < 4; ++r) {
                    float s0 = 0.0f;
                    #pragma unroll
                    for (int ni = 0; ni < 4; ++ni)
                        s0 += __builtin_amdgcn_exp2f(
                            fminf(fmaf(acc[h][mi][ni][r], S_LOG2E_F, -S_LOG2E_F), 0.0f));
                    rowsum[h][mi][r] += s0;
                }

        __syncthreads();   // prefetch landed; cur buffer free
        cur ^= 1;
    }

    // ---- reduce: 16 l15-lanes in-wave, then 2 wn-cols via LDS
    #pragma unroll
    for (int h = 0; h < 2; ++h)
        #pragma unroll
        for (int mi = 0; mi < 2; ++mi)
            #pragma unroll
            for (int r = 0; r < 4; ++r) {
                float s = rowsum[h][mi][r];
                s += __shfl_xor(s, 1);
                s += __shfl_xor(s, 2);
                s += __shfl_xor(s, 4);
                s += __shfl_xor(s, 8);
                rowsum[h][mi][r] = s;
            }
    if (l15 == 0) {
        #pragma unroll
        for (int h = 0; h < 2; ++h)
            #pragma unroll
            for (int mi = 0; mi < 2; ++mi)
                #pragma unroll
                for (int r = 0; r < 4; ++r)
                    rs[wn][h * 128 + wm * 32 + mi * 16 + g4 * 4 + r] = rowsum[h][mi][r];
    }
    __syncthreads();
    if (tid < BM)
        P[(size_t)g * B_SZ + bi * BM + tid] = rs[0][tid] + rs[1][tid];
#undef STAGE
}

// ---- Kernel D: per-row S reduce + EXACT f32 target dot/norm + nll,
// atomically accumulated into out[0] (zeroed by norm_conv).
__global__ void row_fin(const float* __restrict__ P, const float* __restrict__ E,
                        const float* __restrict__ W, const int* __restrict__ lab,
                        float* __restrict__ out) {
    __shared__ float red[256];
    __shared__ float red2[128];
    const int row = blockIdx.x;
    const int t   = threadIdx.x;

    red[t] = (t < NG) ? P[(size_t)t * B_SZ + row] : 0.0f;
    __syncthreads();
    #pragma unroll
    for (int off = 128; off > 0; off >>= 1) {
        if (t < off) red[t] += red[t + off];
        __syncthreads();
    }
    const float S = red[0];
    __syncthreads();

    const int lb = lab[row];
    if (t < 128) {
        const float w = W[(size_t)lb * D_SZ + t];
        const float e = E[(size_t)row * D_SZ + t];
        red[t]  = e * w;
        red2[t] = w * w;
    } else {
        red[t] = 0.0f;
    }
    __syncthreads();
    #pragma unroll
    for (int off = 64; off > 0; off >>= 1) {
        if (t < off) { red[t] += red[t + off]; red2[t] += red2[t + off]; }
        __syncthreads();
    }

    if (t == 0) {
        const float ct = red[0] / fmaxf(sqrtf(red2[0]), 1e-12f);
        const float cc = fminf(fmaxf(ct, -CLIP_F), CLIP_F);
        const float lt = SCALE_F * (cc - MARGIN_F);
        // swap the target's (fp8-noisy, clipped) S-term for the exact one
        float Sadj = S - exp2f(fminf((SCALE_F * cc - SCALE_F) * LOG2E_F, 0.0f))
                       + exp2f((lt - SCALE_F) * LOG2E_F);
        atomicAdd(out, (SCALE_F + logf(Sadj) - lt) * (1.0f / 1024.0f));
    }
}

extern "C" void kernel_launch(void* const* d_in, const int* in_sizes, int n_in,
                              void* d_out, int out_size, void* d_ws, size_t ws_size,
                              hipStream_t stream) {
    const float* E   = (const float*)d_in[0];
    const int*   lab = (const int*)d_in[1];
    const float* W   = (const float*)d_in[2];
    float*       out = (float*)d_out;

    char* ws = (char*)d_ws;
    unsigned int* Ef8 = (unsigned int*)ws;                          // 131,072 B
    unsigned int* Wf8 = (unsigned int*)(ws + 131072);               // 12,812,288 B
    float*        P   = (float*)(ws + 131072 + 12812288);           // 524,288 B

    norm_conv<<<dim3(12640),   256, 0, stream>>>(W, Wf8, E, Ef8, out);
    gemm_lse <<<dim3(NG, 4),   512, 0, stream>>>((const unsigned char*)Ef8,
                                                 (const unsigned char*)Wf8, P);
    row_fin  <<<dim3(B_SZ),    256, 0, stream>>>(P, E, W, lab, out);
}

// Round 14
// 63.623 us; speedup vs baseline: 1.1039x; 1.1039x over previous
//
#include <hip/hip_runtime.h>
#include <hip/hip_bf16.h>

typedef float f32x4 __attribute__((ext_vector_type(4)));

#define B_SZ 1024
#define D_SZ 128
#define C_SZ 100000
#define CPAD 100096          // padded class rows (zero tail), 782*128
#define BM 128
#define BN 128
#define NG 64                // C-tile groups (grid.x)
#define NCT 782              // 100096/128

#define SCALE_F   64.0f
#define MARGIN_F  0.35f
#define CLIP_F    (1.0f - 1e-7f)
#define LOG2E_F   1.4426950408889634f
#define S_LOG2E_F (64.0f * 1.4426950408889634f)

__device__ __forceinline__ void gload_lds16(const void* g, void* l) {
    __builtin_amdgcn_global_load_lds(
        (const __attribute__((address_space(1))) void*)g,
        (__attribute__((address_space(3))) void*)l, 16, 0, 0);
}

// ---- Kernel A: L2-normalize W rows -> fp8 e4m3 (+zero pad) + convert E -> fp8.
// Also zeroes out[0] (accumulated by row_fin's atomicAdd).
__global__ void norm_conv(const float* __restrict__ W, unsigned int* __restrict__ Wf8,
                          const float* __restrict__ E, unsigned int* __restrict__ Ef8,
                          float* __restrict__ out) {
    const int b = blockIdx.x;
    if (b < 12512) {
        const int lane = threadIdx.x & 63;
        const int l32  = lane & 31;
        const int row  = b * 8 + ((threadIdx.x >> 6) << 1) + (lane >> 5);
        if (row < C_SZ) {
            float4 v = reinterpret_cast<const float4*>(W + (size_t)row * D_SZ)[l32];
            float ss = v.x * v.x + v.y * v.y + v.z * v.z + v.w * v.w;
            #pragma unroll
            for (int m = 1; m < 32; m <<= 1) ss += __shfl_xor(ss, m);
            float sc = 1.0f / fmaxf(sqrtf(ss), 1e-12f);
            int r = __builtin_amdgcn_cvt_pk_fp8_f32(v.x * sc, v.y * sc, 0, false);
            r     = __builtin_amdgcn_cvt_pk_fp8_f32(v.z * sc, v.w * sc, r, true);
            Wf8[(size_t)row * 32 + l32] = (unsigned int)r;
        } else {   // zero pad rows [C_SZ, CPAD)
            Wf8[(size_t)row * 32 + l32] = 0u;
        }
    } else {
        if (b == 12512 && threadIdx.x == 0) out[0] = 0.0f;
        const int i = (b - 12512) * 256 + threadIdx.x;   // 32768 float4
        float4 v = reinterpret_cast<const float4*>(E)[i];
        int r = __builtin_amdgcn_cvt_pk_fp8_f32(v.x, v.y, 0, false);
        r     = __builtin_amdgcn_cvt_pk_fp8_f32(v.z, v.w, r, true);
        Ef8[i] = (unsigned int)r;
    }
}

// ---- Kernel C: fused GEMM + exp-sum — R12's proven config, verbatim.
// grid (NG=64, 8 bi), 512 thr = 8 waves (4wm x 2wn); wave tile 32 rows x 64 cols.
// mfma_f32_16x16x32_fp8_fp8; tile = 128 rows x 128 B = 16 KB, double-buffered.
__launch_bounds__(512, 3)
__global__ void gemm_lse(const unsigned char* __restrict__ Ef8,
                         const unsigned char* __restrict__ Wf8,
                         float* __restrict__ P) {
    __shared__ unsigned char sB[2][BN * D_SZ];   // 2 x 16 KB
    __shared__ float rs[2][BM];                  // 1 KB cross-wave reduce

    const int tid  = threadIdx.x;
    const int wave = tid >> 6;
    const int lane = tid & 63;
    const int g4   = lane >> 4;
    const int l15  = lane & 15;
    const int wm   = wave >> 1;           // 0..3 : 32-row slice
    const int wn   = wave & 1;            // 0..1 : 64-col slice
    const int g    = blockIdx.x;          // 0..63
    const int bi   = blockIdx.y;          // 0..7

    const int T = (NCT - g + NG - 1) / NG;   // 13 for g<14, else 12

    const char* wbase = reinterpret_cast<const char*>(Wf8);
    // staging source (pre-swizzled): LDS linear p=tid*16, row=p>>7 (128B rows),
    // granule=(p&127)>>4; source granule = granule ^ (row&7).
    const int srcOff = ((tid >> 3) << 7) + ((((tid & 7) ^ ((tid >> 3) & 7))) << 4);
    const int ldsOff = wave << 10;        // wave-uniform dest base within 8KB pass

#define STAGE(TI, BUF)                                                         \
    {                                                                          \
        const char* _s = wbase + (size_t)(TI) * 16384 + srcOff;                \
        char* _d = reinterpret_cast<char*>(BUF) + ldsOff;                      \
        gload_lds16(_s,        _d);                                            \
        gload_lds16(_s + 8192, _d + 8192);                                     \
    }

    // ---- stage first B tile
    STAGE(g, sB[0]);

    // ---- A fragments straight from global (once): 8 fp8 = one i64 per frag.
    long a[2][4];
    {
        const char* ebase = reinterpret_cast<const char*>(Ef8) + (size_t)bi * BM * 128;
        #pragma unroll
        for (int mi = 0; mi < 2; ++mi) {
            const char* pr = ebase + (wm * 32 + mi * 16 + l15) * 128 + g4 * 8;
            #pragma unroll
            for (int kk = 0; kk < 4; ++kk)
                a[mi][kk] = *reinterpret_cast<const long*>(pr + kk * 32);
        }
    }

    // hoisted ds_read offsets: row = wn*64 + ni*16 + l15 (128B rows);
    // byte = (kk*32 + g4*8) ^ ((l15&7)<<4)   (row&7 == l15&7)
    const int swz = (l15 & 7) << 4;
    int rowb[4];
    #pragma unroll
    for (int ni = 0; ni < 4; ++ni) rowb[ni] = (wn * 64 + ni * 16 + l15) << 7;
    int kb[4];
    #pragma unroll
    for (int kk = 0; kk < 4; ++kk) kb[kk] = (kk * 32 + g4 * 8) ^ swz;

    float rowsum[2][4] = {};   // [mi][r]

    __syncthreads();

    int cur = 0;
    for (int t = 0; t < T; ++t) {
        if (t + 1 < T) STAGE(g + (t + 1) * NG, sB[cur ^ 1]);

        const char* sBb = reinterpret_cast<const char*>(sB[cur]);
        f32x4 acc[2][4] = {};
        #pragma unroll
        for (int kk = 0; kk < 4; ++kk) {
            long b[4];
            #pragma unroll
            for (int ni = 0; ni < 4; ++ni)
                b[ni] = *reinterpret_cast<const long*>(sBb + rowb[ni] + kb[kk]);
            #pragma unroll
            for (int mi = 0; mi < 2; ++mi)
                #pragma unroll
                for (int ni = 0; ni < 4; ++ni)
                    acc[mi][ni] = __builtin_amdgcn_mfma_f32_16x16x32_fp8_fp8(
                        a[mi][kk], b[ni], acc[mi][ni], 0, 0, 0);
        }

        // epilogue: rowsum += exp2(min(x*92.33 - 92.33, 0)).
        // Lower clip free (underflow); upper clip = the fmin (bounds every
        // class contribution at 1 -> also bounds fp8 noise inflation of S).
        #pragma unroll
        for (int mi = 0; mi < 2; ++mi) {
            #pragma unroll
            for (int r = 0; r < 4; ++r) {
                float s0 = 0.0f;
                #pragma unroll
                for (int ni = 0; ni < 4; ++ni)
                    s0 += __builtin_amdgcn_exp2f(
                        fminf(fmaf(acc[mi][ni][r], S_LOG2E_F, -S_LOG2E_F), 0.0f));
                rowsum[mi][r] += s0;
            }
        }
        __syncthreads();   // prefetch landed; cur buffer free
        cur ^= 1;
    }

    // ---- reduce: 16 l15-lanes in-wave, then 2 wn-cols via LDS
    #pragma unroll
    for (int mi = 0; mi < 2; ++mi) {
        #pragma unroll
        for (int r = 0; r < 4; ++r) {
            float s = rowsum[mi][r];
            s += __shfl_xor(s, 1);
            s += __shfl_xor(s, 2);
            s += __shfl_xor(s, 4);
            s += __shfl_xor(s, 8);
            rowsum[mi][r] = s;
        }
    }
    if (l15 == 0) {
        #pragma unroll
        for (int mi = 0; mi < 2; ++mi)
            #pragma unroll
            for (int r = 0; r < 4; ++r)
                rs[wn][wm * 32 + mi * 16 + g4 * 4 + r] = rowsum[mi][r];
    }
    __syncthreads();
    if (tid < BM)
        P[(size_t)g * B_SZ + bi * BM + tid] = rs[0][tid] + rs[1][tid];
#undef STAGE
}

// ---- Kernel D: per-row S reduce + EXACT f32 target dot/norm + nll,
// atomically accumulated into out[0] (zeroed by norm_conv).
__global__ void row_fin(const float* __restrict__ P, const float* __restrict__ E,
                        const float* __restrict__ W, const int* __restrict__ lab,
                        float* __restrict__ out) {
    __shared__ float red[256];
    __shared__ float red2[128];
    const int row = blockIdx.x;
    const int t   = threadIdx.x;

    red[t] = (t < NG) ? P[(size_t)t * B_SZ + row] : 0.0f;
    __syncthreads();
    #pragma unroll
    for (int off = 128; off > 0; off >>= 1) {
        if (t < off) red[t] += red[t + off];
        __syncthreads();
    }
    const float S = red[0];
    __syncthreads();

    const int lb = lab[row];
    if (t < 128) {
        const float w = W[(size_t)lb * D_SZ + t];
        const float e = E[(size_t)row * D_SZ + t];
        red[t]  = e * w;
        red2[t] = w * w;
    } else {
        red[t] = 0.0f;
    }
    __syncthreads();
    #pragma unroll
    for (int off = 64; off > 0; off >>= 1) {
        if (t < off) { red[t] += red[t + off]; red2[t] += red2[t + off]; }
        __syncthreads();
    }

    if (t == 0) {
        const float ct = red[0] / fmaxf(sqrtf(red2[0]), 1e-12f);
        const float cc = fminf(fmaxf(ct, -CLIP_F), CLIP_F);
        const float lt = SCALE_F * (cc - MARGIN_F);
        // swap the target's (fp8-noisy, clipped) S-term for the exact one
        float Sadj = S - exp2f(fminf((SCALE_F * cc - SCALE_F) * LOG2E_F, 0.0f))
                       + exp2f((lt - SCALE_F) * LOG2E_F);
        atomicAdd(out, (SCALE_F + logf(Sadj) - lt) * (1.0f / 1024.0f));
    }
}

extern "C" void kernel_launch(void* const* d_in, const int* in_sizes, int n_in,
                              void* d_out, int out_size, void* d_ws, size_t ws_size,
                              hipStream_t stream) {
    const float* E   = (const float*)d_in[0];
    const int*   lab = (const int*)d_in[1];
    const float* W   = (const float*)d_in[2];
    float*       out = (float*)d_out;

    char* ws = (char*)d_ws;
    unsigned int* Ef8 = (unsigned int*)ws;                          // 131,072 B
    unsigned int* Wf8 = (unsigned int*)(ws + 131072);               // 12,812,288 B
    float*        P   = (float*)(ws + 131072 + 12812288);           // 262,144 B

    norm_conv<<<dim3(12640),   256, 0, stream>>>(W, Wf8, E, Ef8, out);
    gemm_lse <<<dim3(NG, 8),   512, 0, stream>>>((const unsigned char*)Ef8,
                                                 (const unsigned char*)Wf8, P);
    row_fin  <<<dim3(B_SZ),    256, 0, stream>>>(P, E, W, lab, out);
}

// Round 15
// 52.784 us; speedup vs baseline: 1.3306x; 1.2053x over previous
//
#include <hip/hip_runtime.h>
#include <hip/hip_bf16.h>

typedef float f32x4 __attribute__((ext_vector_type(4)));

#define B_SZ 1024
#define D_SZ 128
#define C_SZ 100000
#define CPAD 100096          // padded class rows (zero tail), 782*128
#define BM 128
#define BN 128
#define NG 64                // C-tile groups (grid.x)
#define NCT 782              // 100096/128

#define SCALE_F   64.0f
#define MARGIN_F  0.35f
#define CLIP_F    (1.0f - 1e-7f)
#define LOG2E_F   1.4426950408889634f
#define S_LOG2E_F (64.0f * 1.4426950408889634f)

__device__ __forceinline__ void gload_lds16(const void* g, void* l) {
    __builtin_amdgcn_global_load_lds(
        (const __attribute__((address_space(1))) void*)g,
        (__attribute__((address_space(3))) void*)l, 16, 0, 0);
}

// ---- Kernel A: L2-normalize W rows -> fp8 e4m3 (+zero pad) + convert E -> fp8.
__global__ void norm_conv(const float* __restrict__ W, unsigned int* __restrict__ Wf8,
                          const float* __restrict__ E, unsigned int* __restrict__ Ef8) {
    const int b = blockIdx.x;
    if (b < 12512) {
        const int lane = threadIdx.x & 63;
        const int l32  = lane & 31;
        const int row  = b * 8 + ((threadIdx.x >> 6) << 1) + (lane >> 5);
        if (row < C_SZ) {
            float4 v = reinterpret_cast<const float4*>(W + (size_t)row * D_SZ)[l32];
            float ss = v.x * v.x + v.y * v.y + v.z * v.z + v.w * v.w;
            #pragma unroll
            for (int m = 1; m < 32; m <<= 1) ss += __shfl_xor(ss, m);
            float sc = 1.0f / fmaxf(sqrtf(ss), 1e-12f);
            int r = __builtin_amdgcn_cvt_pk_fp8_f32(v.x * sc, v.y * sc, 0, false);
            r     = __builtin_amdgcn_cvt_pk_fp8_f32(v.z * sc, v.w * sc, r, true);
            Wf8[(size_t)row * 32 + l32] = (unsigned int)r;
        } else {   // zero pad rows [C_SZ, CPAD)
            Wf8[(size_t)row * 32 + l32] = 0u;
        }
    } else {
        const int i = (b - 12512) * 256 + threadIdx.x;   // 32768 float4
        float4 v = reinterpret_cast<const float4*>(E)[i];
        int r = __builtin_amdgcn_cvt_pk_fp8_f32(v.x, v.y, 0, false);
        r     = __builtin_amdgcn_cvt_pk_fp8_f32(v.z, v.w, r, true);
        Ef8[i] = (unsigned int)r;
    }
}

// ---- Kernel C: fused GEMM + exp-sum — R12's proven config, verbatim.
// grid (NG=64, 8 bi), 512 thr = 8 waves (4wm x 2wn); wave tile 32 rows x 64 cols.
// mfma_f32_16x16x32_fp8_fp8; tile = 128 rows x 128 B = 16 KB, double-buffered.
__launch_bounds__(512, 3)
__global__ void gemm_lse(const unsigned char* __restrict__ Ef8,
                         const unsigned char* __restrict__ Wf8,
                         float* __restrict__ P) {
    __shared__ unsigned char sB[2][BN * D_SZ];   // 2 x 16 KB
    __shared__ float rs[2][BM];                  // 1 KB cross-wave reduce

    const int tid  = threadIdx.x;
    const int wave = tid >> 6;
    const int lane = tid & 63;
    const int g4   = lane >> 4;
    const int l15  = lane & 15;
    const int wm   = wave >> 1;           // 0..3 : 32-row slice
    const int wn   = wave & 1;            // 0..1 : 64-col slice
    const int g    = blockIdx.x;          // 0..63
    const int bi   = blockIdx.y;          // 0..7

    const int T = (NCT - g + NG - 1) / NG;   // 13 for g<14, else 12

    const char* wbase = reinterpret_cast<const char*>(Wf8);
    // staging source (pre-swizzled): LDS linear p=tid*16, row=p>>7 (128B rows),
    // granule=(p&127)>>4; source granule = granule ^ (row&7).
    const int srcOff = ((tid >> 3) << 7) + ((((tid & 7) ^ ((tid >> 3) & 7))) << 4);
    const int ldsOff = wave << 10;        // wave-uniform dest base within 8KB pass

#define STAGE(TI, BUF)                                                         \
    {                                                                          \
        const char* _s = wbase + (size_t)(TI) * 16384 + srcOff;                \
        char* _d = reinterpret_cast<char*>(BUF) + ldsOff;                      \
        gload_lds16(_s,        _d);                                            \
        gload_lds16(_s + 8192, _d + 8192);                                     \
    }

    // ---- stage first B tile
    STAGE(g, sB[0]);

    // ---- A fragments straight from global (once): 8 fp8 = one i64 per frag.
    long a[2][4];
    {
        const char* ebase = reinterpret_cast<const char*>(Ef8) + (size_t)bi * BM * 128;
        #pragma unroll
        for (int mi = 0; mi < 2; ++mi) {
            const char* pr = ebase + (wm * 32 + mi * 16 + l15) * 128 + g4 * 8;
            #pragma unroll
            for (int kk = 0; kk < 4; ++kk)
                a[mi][kk] = *reinterpret_cast<const long*>(pr + kk * 32);
        }
    }

    // hoisted ds_read offsets: row = wn*64 + ni*16 + l15 (128B rows);
    // byte = (kk*32 + g4*8) ^ ((l15&7)<<4)   (row&7 == l15&7)
    const int swz = (l15 & 7) << 4;
    int rowb[4];
    #pragma unroll
    for (int ni = 0; ni < 4; ++ni) rowb[ni] = (wn * 64 + ni * 16 + l15) << 7;
    int kb[4];
    #pragma unroll
    for (int kk = 0; kk < 4; ++kk) kb[kk] = (kk * 32 + g4 * 8) ^ swz;

    float rowsum[2][4] = {};   // [mi][r]

    __syncthreads();

    int cur = 0;
    for (int t = 0; t < T; ++t) {
        if (t + 1 < T) STAGE(g + (t + 1) * NG, sB[cur ^ 1]);

        const char* sBb = reinterpret_cast<const char*>(sB[cur]);
        f32x4 acc[2][4] = {};
        #pragma unroll
        for (int kk = 0; kk < 4; ++kk) {
            long b[4];
            #pragma unroll
            for (int ni = 0; ni < 4; ++ni)
                b[ni] = *reinterpret_cast<const long*>(sBb + rowb[ni] + kb[kk]);
            #pragma unroll
            for (int mi = 0; mi < 2; ++mi)
                #pragma unroll
                for (int ni = 0; ni < 4; ++ni)
                    acc[mi][ni] = __builtin_amdgcn_mfma_f32_16x16x32_fp8_fp8(
                        a[mi][kk], b[ni], acc[mi][ni], 0, 0, 0);
        }

        // epilogue: rowsum += exp2(min(x*92.33 - 92.33, 0)).
        // Lower clip free (underflow); upper clip = the fmin (bounds every
        // class contribution at 1 -> also bounds fp8 noise inflation of S).
        #pragma unroll
        for (int mi = 0; mi < 2; ++mi) {
            #pragma unroll
            for (int r = 0; r < 4; ++r) {
                float s0 = 0.0f;
                #pragma unroll
                for (int ni = 0; ni < 4; ++ni)
                    s0 += __builtin_amdgcn_exp2f(
                        fminf(fmaf(acc[mi][ni][r], S_LOG2E_F, -S_LOG2E_F), 0.0f));
                rowsum[mi][r] += s0;
            }
        }
        __syncthreads();   // prefetch landed; cur buffer free
        cur ^= 1;
    }

    // ---- reduce: 16 l15-lanes in-wave, then 2 wn-cols via LDS
    #pragma unroll
    for (int mi = 0; mi < 2; ++mi) {
        #pragma unroll
        for (int r = 0; r < 4; ++r) {
            float s = rowsum[mi][r];
            s += __shfl_xor(s, 1);
            s += __shfl_xor(s, 2);
            s += __shfl_xor(s, 4);
            s += __shfl_xor(s, 8);
            rowsum[mi][r] = s;
        }
    }
    if (l15 == 0) {
        #pragma unroll
        for (int mi = 0; mi < 2; ++mi)
            #pragma unroll
            for (int r = 0; r < 4; ++r)
                rs[wn][wm * 32 + mi * 16 + g4 * 4 + r] = rowsum[mi][r];
    }
    __syncthreads();
    if (tid < BM)
        P[(size_t)g * B_SZ + bi * BM + tid] = rs[0][tid] + rs[1][tid];
#undef STAGE
}

// ---- Kernel D1: per-row S reduce + EXACT f32 target dot/norm + nll
__global__ void row_fin(const float* __restrict__ P, const float* __restrict__ E,
                        const float* __restrict__ W, const int* __restrict__ lab,
                        float* __restrict__ nll) {
    __shared__ float red[256];
    __shared__ float red2[128];
    const int row = blockIdx.x;
    const int t   = threadIdx.x;

    red[t] = (t < NG) ? P[(size_t)t * B_SZ + row] : 0.0f;
    __syncthreads();
    #pragma unroll
    for (int off = 128; off > 0; off >>= 1) {
        if (t < off) red[t] += red[t + off];
        __syncthreads();
    }
    const float S = red[0];
    __syncthreads();

    const int lb = lab[row];
    if (t < 128) {
        const float w = W[(size_t)lb * D_SZ + t];
        const float e = E[(size_t)row * D_SZ + t];
        red[t]  = e * w;
        red2[t] = w * w;
    } else {
        red[t] = 0.0f;
    }
    __syncthreads();
    #pragma unroll
    for (int off = 64; off > 0; off >>= 1) {
        if (t < off) { red[t] += red[t + off]; red2[t] += red2[t + off]; }
        __syncthreads();
    }

    if (t == 0) {
        const float ct = red[0] / fmaxf(sqrtf(red2[0]), 1e-12f);
        const float cc = fminf(fmaxf(ct, -CLIP_F), CLIP_F);
        const float lt = SCALE_F * (cc - MARGIN_F);
        // swap the target's (fp8-noisy, clipped) S-term for the exact one
        float Sadj = S - exp2f(fminf((SCALE_F * cc - SCALE_F) * LOG2E_F, 0.0f))
                       + exp2f((lt - SCALE_F) * LOG2E_F);
        nll[row] = SCALE_F + logf(Sadj) - lt;
    }
}

// ---- Kernel D2: mean over 1024 rows (shuffle-based, no atomic contention)
__global__ void mean_k(const float* __restrict__ nll, float* __restrict__ out) {
    __shared__ float part[16];
    const int t = threadIdx.x;
    float v = nll[t];
    #pragma unroll
    for (int m = 1; m < 64; m <<= 1) v += __shfl_xor(v, m);
    if ((t & 63) == 0) part[t >> 6] = v;
    __syncthreads();
    if (t < 16) {
        float u = part[t];
        #pragma unroll
        for (int m = 1; m < 16; m <<= 1) u += __shfl_xor(u, m);
        if (t == 0) out[0] = u * (1.0f / 1024.0f);
    }
}

extern "C" void kernel_launch(void* const* d_in, const int* in_sizes, int n_in,
                              void* d_out, int out_size, void* d_ws, size_t ws_size,
                              hipStream_t stream) {
    const float* E   = (const float*)d_in[0];
    const int*   lab = (const int*)d_in[1];
    const float* W   = (const float*)d_in[2];
    float*       out = (float*)d_out;

    char* ws = (char*)d_ws;
    unsigned int* Ef8 = (unsigned int*)ws;                          // 131,072 B
    unsigned int* Wf8 = (unsigned int*)(ws + 131072);               // 12,812,288 B
    float*        P   = (float*)(ws + 131072 + 12812288);           // 262,144 B
    float*        nll = (float*)(ws + 131072 + 12812288 + 262144);  // 4,096 B

    norm_conv<<<dim3(12640),   256, 0, stream>>>(W, Wf8, E, Ef8);
    gemm_lse <<<dim3(NG, 8),   512, 0, stream>>>((const unsigned char*)Ef8,
                                                 (const unsigned char*)Wf8, P);
    row_fin  <<<dim3(B_SZ),    256, 0, stream>>>(P, E, W, lab, nll);
    mean_k   <<<dim3(1),      1024, 0, stream>>>(nll, out);
}

// Round 16
// 46.075 us; speedup vs baseline: 1.5244x; 1.1456x over previous
//
#include <hip/hip_runtime.h>
#include <hip/hip_bf16.h>

typedef float f32x4 __attribute__((ext_vector_type(4)));
typedef int   i32x4 __attribute__((ext_vector_type(4)));
typedef int   i32x8 __attribute__((ext_vector_type(8)));

#define B_SZ 1024
#define D_SZ 128
#define C_SZ 100000
#define CPAD 100096          // padded class rows (zero tail), 782*128
#define BM 128
#define BN 128
#define NG 64                // C-tile groups (grid.x)
#define NCT 782              // 100096/128

#define SCALE_F   64.0f
#define MARGIN_F  0.35f
#define CLIP_F    (1.0f - 1e-7f)
#define LOG2E_F   1.4426950408889634f
#define S_LOG2E_F (64.0f * 1.4426950408889634f)
#define UNIT_SCALE 0x7F7F7F7F   // e8m0 127 = 2^0 in every byte

__device__ __forceinline__ void gload_lds16(const void* g, void* l) {
    __builtin_amdgcn_global_load_lds(
        (const __attribute__((address_space(1))) void*)g,
        (__attribute__((address_space(3))) void*)l, 16, 0, 0);
}

// ---- Kernel A: L2-normalize W rows -> fp8 e4m3 (+zero pad) + convert E -> fp8.
__global__ void norm_conv(const float* __restrict__ W, unsigned int* __restrict__ Wf8,
                          const float* __restrict__ E, unsigned int* __restrict__ Ef8) {
    const int b = blockIdx.x;
    if (b < 12512) {
        const int lane = threadIdx.x & 63;
        const int l32  = lane & 31;
        const int row  = b * 8 + ((threadIdx.x >> 6) << 1) + (lane >> 5);
        if (row < C_SZ) {
            float4 v = reinterpret_cast<const float4*>(W + (size_t)row * D_SZ)[l32];
            float ss = v.x * v.x + v.y * v.y + v.z * v.z + v.w * v.w;
            #pragma unroll
            for (int m = 1; m < 32; m <<= 1) ss += __shfl_xor(ss, m);
            float sc = 1.0f / fmaxf(sqrtf(ss), 1e-12f);
            int r = __builtin_amdgcn_cvt_pk_fp8_f32(v.x * sc, v.y * sc, 0, false);
            r     = __builtin_amdgcn_cvt_pk_fp8_f32(v.z * sc, v.w * sc, r, true);
            Wf8[(size_t)row * 32 + l32] = (unsigned int)r;
        } else {   // zero pad rows [C_SZ, CPAD)
            Wf8[(size_t)row * 32 + l32] = 0u;
        }
    } else {
        const int i = (b - 12512) * 256 + threadIdx.x;   // 32768 float4
        float4 v = reinterpret_cast<const float4*>(E)[i];
        int r = __builtin_amdgcn_cvt_pk_fp8_f32(v.x, v.y, 0, false);
        r     = __builtin_amdgcn_cvt_pk_fp8_f32(v.z, v.w, r, true);
        Ef8[i] = (unsigned int)r;
    }
}

// ---- Kernel C: fused GEMM + exp-sum — R12/R15 skeleton, MX-scaled fp8 MFMA.
// grid (NG=64, 8 bi), 512 thr = 8 waves (4wm x 2wn); wave tile 32 rows x 64 cols.
// mfma_scale_f32_16x16x128_f8f6f4, unit scales: ONE instruction covers K=128
// -> 8 MFMA/tile (was 32), 2x pipe rate. Fragment = 32B/lane (k = g4*32..+32).
// LDS layout/swizzle identical to R15; reads become 2x b128 per fragment.
__launch_bounds__(512, 3)
__global__ void gemm_lse(const unsigned char* __restrict__ Ef8,
                         const unsigned char* __restrict__ Wf8,
                         float* __restrict__ P) {
    __shared__ unsigned char sB[2][BN * D_SZ];   // 2 x 16 KB
    __shared__ float rs[2][BM];                  // 1 KB cross-wave reduce

    const int tid  = threadIdx.x;
    const int wave = tid >> 6;
    const int lane = tid & 63;
    const int g4   = lane >> 4;
    const int l15  = lane & 15;
    const int wm   = wave >> 1;           // 0..3 : 32-row slice
    const int wn   = wave & 1;            // 0..1 : 64-col slice
    const int g    = blockIdx.x;          // 0..63
    const int bi   = blockIdx.y;          // 0..7

    const int T = (NCT - g + NG - 1) / NG;   // 13 for g<14, else 12

    const char* wbase = reinterpret_cast<const char*>(Wf8);
    // staging source (pre-swizzled): LDS linear p=tid*16, row=p>>7 (128B rows),
    // granule=(p&127)>>4; source granule = granule ^ (row&7).
    const int srcOff = ((tid >> 3) << 7) + ((((tid & 7) ^ ((tid >> 3) & 7))) << 4);
    const int ldsOff = wave << 10;        // wave-uniform dest base within 8KB pass

#define STAGE(TI, BUF)                                                         \
    {                                                                          \
        const char* _s = wbase + (size_t)(TI) * 16384 + srcOff;                \
        char* _d = reinterpret_cast<char*>(BUF) + ldsOff;                      \
        gload_lds16(_s,        _d);                                            \
        gload_lds16(_s + 8192, _d + 8192);                                     \
    }

    // ---- stage first B tile
    STAGE(g, sB[0]);

    // ---- A fragments straight from global (once): 32 fp8 = i32x8 per frag.
    // row = wm*32 + mi*16 + l15, k-bytes = g4*32 .. +32.
    i32x8 a[2];
    {
        const char* ebase = reinterpret_cast<const char*>(Ef8) + (size_t)bi * BM * 128;
        #pragma unroll
        for (int mi = 0; mi < 2; ++mi) {
            const char* pr = ebase + (wm * 32 + mi * 16 + l15) * 128 + g4 * 32;
            i32x4 lo = *reinterpret_cast<const i32x4*>(pr);
            i32x4 hi = *reinterpret_cast<const i32x4*>(pr + 16);
            #pragma unroll
            for (int j = 0; j < 4; ++j) { a[mi][j] = lo[j]; a[mi][4 + j] = hi[j]; }
        }
    }

    // hoisted ds_read offsets: row = wn*64 + ni*16 + l15 (128B rows);
    // two 16B granules at (g4*32)^swz and (g4*32+16)^swz (same involution
    // the staging source applied -> reads linear [row][g4*32..+32)).
    const int swz = (l15 & 7) << 4;
    int rowb[4];
    #pragma unroll
    for (int ni = 0; ni < 4; ++ni) rowb[ni] = (wn * 64 + ni * 16 + l15) << 7;
    const int kb0 = (g4 * 32) ^ swz;
    const int kb1 = (g4 * 32 + 16) ^ swz;

    float rowsum[2][4] = {};   // [mi][r]

    __syncthreads();

    int cur = 0;
    for (int t = 0; t < T; ++t) {
        if (t + 1 < T) STAGE(g + (t + 1) * NG, sB[cur ^ 1]);

        const char* sBb = reinterpret_cast<const char*>(sB[cur]);
        f32x4 acc[2][4] = {};
        #pragma unroll
        for (int ni = 0; ni < 4; ++ni) {
            i32x4 blo = *reinterpret_cast<const i32x4*>(sBb + rowb[ni] + kb0);
            i32x4 bhi = *reinterpret_cast<const i32x4*>(sBb + rowb[ni] + kb1);
            i32x8 b;
            #pragma unroll
            for (int j = 0; j < 4; ++j) { b[j] = blo[j]; b[4 + j] = bhi[j]; }
            #pragma unroll
            for (int mi = 0; mi < 2; ++mi)
                acc[mi][ni] = __builtin_amdgcn_mfma_scale_f32_16x16x128_f8f6f4(
                    a[mi], b, acc[mi][ni], 0, 0,   // cbsz=fp8, blgp=fp8
                    0, UNIT_SCALE, 0, UNIT_SCALE); // opsel/scale A, opsel/scale B
        }

        // epilogue: rowsum += exp2(min(x*92.33 - 92.33, 0)).
        // Lower clip free (underflow); upper clip = the fmin (bounds every
        // class contribution at 1 -> also bounds fp8 noise inflation of S).
        #pragma unroll
        for (int mi = 0; mi < 2; ++mi) {
            #pragma unroll
            for (int r = 0; r < 4; ++r) {
                float s0 = 0.0f;
                #pragma unroll
                for (int ni = 0; ni < 4; ++ni)
                    s0 += __builtin_amdgcn_exp2f(
                        fminf(fmaf(acc[mi][ni][r], S_LOG2E_F, -S_LOG2E_F), 0.0f));
                rowsum[mi][r] += s0;
            }
        }
        __syncthreads();   // prefetch landed; cur buffer free
        cur ^= 1;
    }

    // ---- reduce: 16 l15-lanes in-wave, then 2 wn-cols via LDS
    #pragma unroll
    for (int mi = 0; mi < 2; ++mi) {
        #pragma unroll
        for (int r = 0; r < 4; ++r) {
            float s = rowsum[mi][r];
            s += __shfl_xor(s, 1);
            s += __shfl_xor(s, 2);
            s += __shfl_xor(s, 4);
            s += __shfl_xor(s, 8);
            rowsum[mi][r] = s;
        }
    }
    if (l15 == 0) {
        #pragma unroll
        for (int mi = 0; mi < 2; ++mi)
            #pragma unroll
            for (int r = 0; r < 4; ++r)
                rs[wn][wm * 32 + mi * 16 + g4 * 4 + r] = rowsum[mi][r];
    }
    __syncthreads();
    if (tid < BM)
        P[(size_t)g * B_SZ + bi * BM + tid] = rs[0][tid] + rs[1][tid];
#undef STAGE
}

// ---- Kernel D1: per-row S reduce + EXACT f32 target dot/norm + nll
__global__ void row_fin(const float* __restrict__ P, const float* __restrict__ E,
                        const float* __restrict__ W, const int* __restrict__ lab,
                        float* __restrict__ nll) {
    __shared__ float red[256];
    __shared__ float red2[128];
    const int row = blockIdx.x;
    const int t   = threadIdx.x;

    red[t] = (t < NG) ? P[(size_t)t * B_SZ + row] : 0.0f;
    __syncthreads();
    #pragma unroll
    for (int off = 128; off > 0; off >>= 1) {
        if (t < off) red[t] += red[t + off];
        __syncthreads();
    }
    const float S = red[0];
    __syncthreads();

    const int lb = lab[row];
    if (t < 128) {
        const float w = W[(size_t)lb * D_SZ + t];
        const float e = E[(size_t)row * D_SZ + t];
        red[t]  = e * w;
        red2[t] = w * w;
    } else {
        red[t] = 0.0f;
    }
    __syncthreads();
    #pragma unroll
    for (int off = 64; off > 0; off >>= 1) {
        if (t < off) { red[t] += red[t + off]; red2[t] += red2[t + off]; }
        __syncthreads();
    }

    if (t == 0) {
        const float ct = red[0] / fmaxf(sqrtf(red2[0]), 1e-12f);
        const float cc = fminf(fmaxf(ct, -CLIP_F), CLIP_F);
        const float lt = SCALE_F * (cc - MARGIN_F);
        // swap the target's (fp8-noisy, clipped) S-term for the exact one
        float Sadj = S - exp2f(fminf((SCALE_F * cc - SCALE_F) * LOG2E_F, 0.0f))
                       + exp2f((lt - SCALE_F) * LOG2E_F);
        nll[row] = SCALE_F + logf(Sadj) - lt;
    }
}

// ---- Kernel D2: mean over 1024 rows (shuffle-based, no atomic contention)
__global__ void mean_k(const float* __restrict__ nll, float* __restrict__ out) {
    __shared__ float part[16];
    const int t = threadIdx.x;
    float v = nll[t];
    #pragma unroll
    for (int m = 1; m < 64; m <<= 1) v += __shfl_xor(v, m);
    if ((t & 63) == 0) part[t >> 6] = v;
    __syncthreads();
    if (t < 16) {
        float u = part[t];
        #pragma unroll
        for (int m = 1; m < 16; m <<= 1) u += __shfl_xor(u, m);
        if (t == 0) out[0] = u * (1.0f / 1024.0f);
    }
}

extern "C" void kernel_launch(void* const* d_in, const int* in_sizes, int n_in,
                              void* d_out, int out_size, void* d_ws, size_t ws_size,
                              hipStream_t stream) {
    const float* E   = (const float*)d_in[0];
    const int*   lab = (const int*)d_in[1];
    const float* W   = (const float*)d_in[2];
    float*       out = (float*)d_out;

    char* ws = (char*)d_ws;
    unsigned int* Ef8 = (unsigned int*)ws;                          // 131,072 B
    unsigned int* Wf8 = (unsigned int*)(ws + 131072);               // 12,812,288 B
    float*        P   = (float*)(ws + 131072 + 12812288);           // 262,144 B
    float*        nll = (float*)(ws + 131072 + 12812288 + 262144);  // 4,096 B

    norm_conv<<<dim3(12640),   256, 0, stream>>>(W, Wf8, E, Ef8);
    gemm_lse <<<dim3(NG, 8),   512, 0, stream>>>((const unsigned char*)Ef8,
                                                 (const unsigned char*)Wf8, P);
    row_fin  <<<dim3(B_SZ),    256, 0, stream>>>(P, E, W, lab, nll);
    mean_k   <<<dim3(1),      1024, 0, stream>>>(nll, out);
}

// Round 17
// 45.836 us; speedup vs baseline: 1.5323x; 1.0052x over previous
//
#include <hip/hip_runtime.h>
#include <hip/hip_bf16.h>

typedef float f32x4 __attribute__((ext_vector_type(4)));
typedef int   i32x4 __attribute__((ext_vector_type(4)));
typedef int   i32x8 __attribute__((ext_vector_type(8)));

#define B_SZ 1024
#define D_SZ 128
#define C_SZ 100000
#define CPAD 100096          // padded class rows (zero tail), 782*128
#define BM 128
#define BN 128
#define NG 64                // C-tile groups (grid.x)
#define NCT 782              // 100096/128

#define SCALE_F   64.0f
#define MARGIN_F  0.35f
#define CLIP_F    (1.0f - 1e-7f)
#define LOG2E_F   1.4426950408889634f
#define S_LOG2E_F (64.0f * 1.4426950408889634f)
#define UNIT_SCALE 0x7F7F7F7F   // e8m0 127 = 2^0 in every byte

__device__ __forceinline__ void gload_lds16(const void* g, void* l) {
    __builtin_amdgcn_global_load_lds(
        (const __attribute__((address_space(1))) void*)g,
        (__attribute__((address_space(3))) void*)l, 16, 0, 0);
}

// ---- Kernel A: L2-normalize W rows -> fp8 e4m3 (+zero pad) + convert E -> fp8.
__global__ void norm_conv(const float* __restrict__ W, unsigned int* __restrict__ Wf8,
                          const float* __restrict__ E, unsigned int* __restrict__ Ef8) {
    const int b = blockIdx.x;
    if (b < 12512) {
        const int lane = threadIdx.x & 63;
        const int l32  = lane & 31;
        const int row  = b * 8 + ((threadIdx.x >> 6) << 1) + (lane >> 5);
        if (row < C_SZ) {
            float4 v = reinterpret_cast<const float4*>(W + (size_t)row * D_SZ)[l32];
            float ss = v.x * v.x + v.y * v.y + v.z * v.z + v.w * v.w;
            #pragma unroll
            for (int m = 1; m < 32; m <<= 1) ss += __shfl_xor(ss, m);
            float sc = 1.0f / fmaxf(sqrtf(ss), 1e-12f);
            int r = __builtin_amdgcn_cvt_pk_fp8_f32(v.x * sc, v.y * sc, 0, false);
            r     = __builtin_amdgcn_cvt_pk_fp8_f32(v.z * sc, v.w * sc, r, true);
            Wf8[(size_t)row * 32 + l32] = (unsigned int)r;
        } else {   // zero pad rows [C_SZ, CPAD)
            Wf8[(size_t)row * 32 + l32] = 0u;
        }
    } else {
        const int i = (b - 12512) * 256 + threadIdx.x;   // 32768 float4
        float4 v = reinterpret_cast<const float4*>(E)[i];
        int r = __builtin_amdgcn_cvt_pk_fp8_f32(v.x, v.y, 0, false);
        r     = __builtin_amdgcn_cvt_pk_fp8_f32(v.z, v.w, r, true);
        Ef8[i] = (unsigned int)r;
    }
}

// ---- Kernel C: fused GEMM + exp-sum — R12/R15 skeleton, MX-scaled fp8 MFMA.
// grid (NG=64, 8 bi), 512 thr = 8 waves (4wm x 2wn); wave tile 32 rows x 64 cols.
// mfma_scale_f32_16x16x128_f8f6f4, unit scales: ONE instruction covers K=128
// -> 8 MFMA/tile (was 32), 2x pipe rate. Fragment = 32B/lane (k = g4*32..+32).
// LDS layout/swizzle identical to R15; reads become 2x b128 per fragment.
__launch_bounds__(512, 3)
__global__ void gemm_lse(const unsigned char* __restrict__ Ef8,
                         const unsigned char* __restrict__ Wf8,
                         float* __restrict__ P) {
    __shared__ unsigned char sB[2][BN * D_SZ];   // 2 x 16 KB
    __shared__ float rs[2][BM];                  // 1 KB cross-wave reduce

    const int tid  = threadIdx.x;
    const int wave = tid >> 6;
    const int lane = tid & 63;
    const int g4   = lane >> 4;
    const int l15  = lane & 15;
    const int wm   = wave >> 1;           // 0..3 : 32-row slice
    const int wn   = wave & 1;            // 0..1 : 64-col slice
    const int g    = blockIdx.x;          // 0..63
    const int bi   = blockIdx.y;          // 0..7

    const int T = (NCT - g + NG - 1) / NG;   // 13 for g<14, else 12

    const char* wbase = reinterpret_cast<const char*>(Wf8);
    // staging source (pre-swizzled): LDS linear p=tid*16, row=p>>7 (128B rows),
    // granule=(p&127)>>4; source granule = granule ^ (row&7).
    const int srcOff = ((tid >> 3) << 7) + ((((tid & 7) ^ ((tid >> 3) & 7))) << 4);
    const int ldsOff = wave << 10;        // wave-uniform dest base within 8KB pass

#define STAGE(TI, BUF)                                                         \
    {                                                                          \
        const char* _s = wbase + (size_t)(TI) * 16384 + srcOff;                \
        char* _d = reinterpret_cast<char*>(BUF) + ldsOff;                      \
        gload_lds16(_s,        _d);                                            \
        gload_lds16(_s + 8192, _d + 8192);                                     \
    }

    // ---- stage first B tile
    STAGE(g, sB[0]);

    // ---- A fragments straight from global (once): 32 fp8 = i32x8 per frag.
    // row = wm*32 + mi*16 + l15, k-bytes = g4*32 .. +32.
    i32x8 a[2];
    {
        const char* ebase = reinterpret_cast<const char*>(Ef8) + (size_t)bi * BM * 128;
        #pragma unroll
        for (int mi = 0; mi < 2; ++mi) {
            const char* pr = ebase + (wm * 32 + mi * 16 + l15) * 128 + g4 * 32;
            i32x4 lo = *reinterpret_cast<const i32x4*>(pr);
            i32x4 hi = *reinterpret_cast<const i32x4*>(pr + 16);
            #pragma unroll
            for (int j = 0; j < 4; ++j) { a[mi][j] = lo[j]; a[mi][4 + j] = hi[j]; }
        }
    }

    // hoisted ds_read offsets: row = wn*64 + ni*16 + l15 (128B rows);
    // two 16B granules at (g4*32)^swz and (g4*32+16)^swz (same involution
    // the staging source applied -> reads linear [row][g4*32..+32)).
    const int swz = (l15 & 7) << 4;
    int rowb[4];
    #pragma unroll
    for (int ni = 0; ni < 4; ++ni) rowb[ni] = (wn * 64 + ni * 16 + l15) << 7;
    const int kb0 = (g4 * 32) ^ swz;
    const int kb1 = (g4 * 32 + 16) ^ swz;

    float rowsum[2][4] = {};   // [mi][r]

    __syncthreads();

    int cur = 0;
    for (int t = 0; t < T; ++t) {
        if (t + 1 < T) STAGE(g + (t + 1) * NG, sB[cur ^ 1]);

        const char* sBb = reinterpret_cast<const char*>(sB[cur]);
        f32x4 acc[2][4] = {};
        #pragma unroll
        for (int ni = 0; ni < 4; ++ni) {
            i32x4 blo = *reinterpret_cast<const i32x4*>(sBb + rowb[ni] + kb0);
            i32x4 bhi = *reinterpret_cast<const i32x4*>(sBb + rowb[ni] + kb1);
            i32x8 b;
            #pragma unroll
            for (int j = 0; j < 4; ++j) { b[j] = blo[j]; b[4 + j] = bhi[j]; }
            #pragma unroll
            for (int mi = 0; mi < 2; ++mi)
                acc[mi][ni] = __builtin_amdgcn_mfma_scale_f32_16x16x128_f8f6f4(
                    a[mi], b, acc[mi][ni], 0, 0,   // cbsz=fp8, blgp=fp8
                    0, UNIT_SCALE, 0, UNIT_SCALE); // opsel/scale A, opsel/scale B
        }

        // epilogue: rowsum += exp2(min(x*92.33 - 92.33, 0)).
        // Lower clip free (underflow); upper clip = the fmin (bounds every
        // class contribution at 1 -> also bounds fp8 noise inflation of S).
        #pragma unroll
        for (int mi = 0; mi < 2; ++mi) {
            #pragma unroll
            for (int r = 0; r < 4; ++r) {
                float s0 = 0.0f;
                #pragma unroll
                for (int ni = 0; ni < 4; ++ni)
                    s0 += __builtin_amdgcn_exp2f(
                        fminf(fmaf(acc[mi][ni][r], S_LOG2E_F, -S_LOG2E_F), 0.0f));
                rowsum[mi][r] += s0;
            }
        }
        __syncthreads();   // prefetch landed; cur buffer free
        cur ^= 1;
    }

    // ---- reduce: 16 l15-lanes in-wave, then 2 wn-cols via LDS
    #pragma unroll
    for (int mi = 0; mi < 2; ++mi) {
        #pragma unroll
        for (int r = 0; r < 4; ++r) {
            float s = rowsum[mi][r];
            s += __shfl_xor(s, 1);
            s += __shfl_xor(s, 2);
            s += __shfl_xor(s, 4);
            s += __shfl_xor(s, 8);
            rowsum[mi][r] = s;
        }
    }
    if (l15 == 0) {
        #pragma unroll
        for (int mi = 0; mi < 2; ++mi)
            #pragma unroll
            for (int r = 0; r < 4; ++r)
                rs[wn][wm * 32 + mi * 16 + g4 * 4 + r] = rowsum[mi][r];
    }
    __syncthreads();
    if (tid < BM)
        P[(size_t)g * B_SZ + bi * BM + tid] = rs[0][tid] + rs[1][tid];
#undef STAGE
}

// ---- Kernel D1: per-row S reduce + EXACT f32 target dot/norm + nll
__global__ void row_fin(const float* __restrict__ P, const float* __restrict__ E,
                        const float* __restrict__ W, const int* __restrict__ lab,
                        float* __restrict__ nll) {
    __shared__ float red[256];
    __shared__ float red2[128];
    const int row = blockIdx.x;
    const int t   = threadIdx.x;

    red[t] = (t < NG) ? P[(size_t)t * B_SZ + row] : 0.0f;
    __syncthreads();
    #pragma unroll
    for (int off = 128; off > 0; off >>= 1) {
        if (t < off) red[t] += red[t + off];
        __syncthreads();
    }
    const float S = red[0];
    __syncthreads();

    const int lb = lab[row];
    if (t < 128) {
        const float w = W[(size_t)lb * D_SZ + t];
        const float e = E[(size_t)row * D_SZ + t];
        red[t]  = e * w;
        red2[t] = w * w;
    } else {
        red[t] = 0.0f;
    }
    __syncthreads();
    #pragma unroll
    for (int off = 64; off > 0; off >>= 1) {
        if (t < off) { red[t] += red[t + off]; red2[t] += red2[t + off]; }
        __syncthreads();
    }

    if (t == 0) {
        const float ct = red[0] / fmaxf(sqrtf(red2[0]), 1e-12f);
        const float cc = fminf(fmaxf(ct, -CLIP_F), CLIP_F);
        const float lt = SCALE_F * (cc - MARGIN_F);
        // swap the target's (fp8-noisy, clipped) S-term for the exact one
        float Sadj = S - exp2f(fminf((SCALE_F * cc - SCALE_F) * LOG2E_F, 0.0f))
                       + exp2f((lt - SCALE_F) * LOG2E_F);
        nll[row] = SCALE_F + logf(Sadj) - lt;
    }
}

// ---- Kernel D2: mean over 1024 rows (shuffle-based, no atomic contention)
__global__ void mean_k(const float* __restrict__ nll, float* __restrict__ out) {
    __shared__ float part[16];
    const int t = threadIdx.x;
    float v = nll[t];
    #pragma unroll
    for (int m = 1; m < 64; m <<= 1) v += __shfl_xor(v, m);
    if ((t & 63) == 0) part[t >> 6] = v;
    __syncthreads();
    if (t < 16) {
        float u = part[t];
        #pragma unroll
        for (int m = 1; m < 16; m <<= 1) u += __shfl_xor(u, m);
        if (t == 0) out[0] = u * (1.0f / 1024.0f);
    }
}

extern "C" void kernel_launch(void* const* d_in, const int* in_sizes, int n_in,
                              void* d_out, int out_size, void* d_ws, size_t ws_size,
                              hipStream_t stream) {
    const float* E   = (const float*)d_in[0];
    const int*   lab = (const int*)d_in[1];
    const float* W   = (const float*)d_in[2];
    float*       out = (float*)d_out;

    char* ws = (char*)d_ws;
    unsigned int* Ef8 = (unsigned int*)ws;                          // 131,072 B
    unsigned int* Wf8 = (unsigned int*)(ws + 131072);               // 12,812,288 B
    float*        P   = (float*)(ws + 131072 + 12812288);           // 262,144 B
    float*        nll = (float*)(ws + 131072 + 12812288 + 262144);  // 4,096 B

    norm_conv<<<dim3(12640),   256, 0, stream>>>(W, Wf8, E, Ef8);
    gemm_lse <<<dim3(NG, 8),   512, 0, stream>>>((const unsigned char*)Ef8,
                                                 (const unsigned char*)Wf8, P);
    row_fin  <<<dim3(B_SZ),    256, 0, stream>>>(P, E, W, lab, nll);
    mean_k   <<<dim3(1),      1024, 0, stream>>>(nll, out);
}